// Round 1
// baseline (455.057 us; speedup 1.0000x reference)
//
#include <hip/hip_runtime.h>
#include <hip/hip_bf16.h>

#define DIM 64
#define NREL 8
#define KS 512              // Sx width (k-permuted: k = ch*8 + r)
#define KTOT 576            // GEMM K: 512 + 64 root
#define DSTR 4              // deg8 cell stride in ints (16B/cell: 4 cells per 64B line,
                            // cuts atomic line-contention 4x vs dense layout)

typedef __bf16 bf16x8 __attribute__((ext_vector_type(8)));
typedef __bf16 bf16x4 __attribute__((ext_vector_type(4)));
typedef float  f32x4  __attribute__((ext_vector_type(4)));

// ---------------- fused: hist (rank-returning) + initial gather + sentinels ----------------
__global__ __launch_bounds__(256) void histgather_kernel(const int* __restrict__ dst,
                                                         const int* __restrict__ et,
                                                         int* __restrict__ deg8,
                                                         int* __restrict__ eoff,
                                                         const int* __restrict__ x_idx,
                                                         const float* __restrict__ emb,
                                                         __bf16* __restrict__ xb0,
                                                         __bf16* __restrict__ xb1,
                                                         int* __restrict__ srcs,
                                                         int N, int E, int epad_cap) {
    int i = blockIdx.x * 256 + threadIdx.x;
    if (i < N * DIM) {
        int n = i >> 6;
        int c = i & 63;
        xb0[i] = (__bf16)emb[(size_t)x_idx[n] * DIM + c];
    }
    if (i < DIM) {                                        // sentinel zero rows (index N)
        xb0[(size_t)N * DIM + i] = (__bf16)0.f;
        xb1[(size_t)N * DIM + i] = (__bf16)0.f;
    }
    if (i < epad_cap) srcs[i] = N;                        // padding -> sentinel
    if (i < E) eoff[i] = atomicAdd(&deg8[(dst[i] * 8 + et[i]) * DSTR], 1);  // rank within cell
}

// ---------------- scan1 over per-dst PADDED totals + invdeg (true deg) ----------------
__global__ __launch_bounds__(256) void scan1_kernel(const int* __restrict__ deg8,
                                                    int* __restrict__ offs,
                                                    int* __restrict__ bsum,
                                                    float* __restrict__ invdeg, int N) {
    __shared__ int sd[256];
    int tid = threadIdx.x;
    int d = blockIdx.x * 256 + tid;
    int vpad = 0;
    if (d < N) {
        int vtrue = 0;
#pragma unroll
        for (int r = 0; r < NREL; ++r) {
            int dv = deg8[(d * 8 + r) * DSTR];
            vtrue += dv;
            vpad += (dv + 3) & ~3;
        }
        invdeg[d] = 1.0f / fmaxf((float)vtrue, 1.0f);
    }
    sd[tid] = vpad;
    __syncthreads();
#pragma unroll
    for (int off = 1; off < 256; off <<= 1) {
        int t = (tid >= off) ? sd[tid - off] : 0;
        __syncthreads();
        sd[tid] += t;
        __syncthreads();
    }
    if (d < N) offs[d] = sd[tid] - vpad;
    if (tid == 255) bsum[blockIdx.x] = sd[255];
}

// ---------------- scan2 (block 0) + wcat (blocks >= 1) fused ----------------
// Wt[l][c][k]: k<512 -> k=ch*8+r maps weight[l][r][ch][c]; k>=512 -> root[l][k-512][c]
__global__ __launch_bounds__(512) void scan2wcat_kernel(int* __restrict__ bsum, int nb,
                                                        const float* __restrict__ weight,
                                                        const float* __restrict__ root,
                                                        __bf16* __restrict__ Wt, int L) {
    if (blockIdx.x == 0) {
        __shared__ int sd[512];
        int tid = threadIdx.x;
        int v = (tid < nb) ? bsum[tid] : 0;
        sd[tid] = v;
        __syncthreads();
#pragma unroll
        for (int off = 1; off < 512; off <<= 1) {
            int t = (tid >= off) ? sd[tid - off] : 0;
            __syncthreads();
            sd[tid] += t;
            __syncthreads();
        }
        if (tid < nb) bsum[tid] = sd[tid] - v;
    } else {
        int idx = (blockIdx.x - 1) * 512 + threadIdx.x;
        int total = L * 64 * KTOT;
        if (idx >= total) return;
        int l = idx / (64 * KTOT);
        int rem = idx - l * 64 * KTOT;
        int c = rem / KTOT;
        int k = rem - c * KTOT;
        float w;
        if (k < KS) {
            int ch = k >> 3, r = k & 7;
            w = weight[(((l * 8 + r) * 64) + ch) * 64 + c];
        } else {
            w = root[(l * 64 + (k - KS)) * 64 + c];
        }
        Wt[idx] = (__bf16)w;
    }
}

// ---------------- rp_pad build (padded per-cell starts) ----------------
__global__ __launch_bounds__(256) void rpbuild_kernel(const int* __restrict__ deg8,
                                                      const int* __restrict__ offs,
                                                      const int* __restrict__ bsum,
                                                      int* __restrict__ rp,
                                                      int N) {
    int d = blockIdx.x * 256 + threadIdx.x;
    if (d >= N) return;
    int base = offs[d] + bsum[blockIdx.x];
    int run = 0;
#pragma unroll
    for (int r = 0; r < NREL; ++r) {
        rp[d * 8 + r] = base + run;
        run += (deg8[(d * 8 + r) * DSTR] + 3) & ~3;
    }
    if (d == N - 1) rp[(size_t)N * 8] = base + run;   // E_pad total
}

// ---------------- bucket: atomic-free scatter, 2 coalesced half-streams per thread
__global__ __launch_bounds__(256) void bucket_kernel(const int* __restrict__ src,
                                                     const int* __restrict__ dst,
                                                     const int* __restrict__ et,
                                                     const int* __restrict__ rp,
                                                     const int* __restrict__ eoff,
                                                     int* __restrict__ srcs, int E) {
    int i = blockIdx.x * 256 + threadIdx.x;
    int half = (E + 1) >> 1;
    if (i >= half) return;
    int iB = i + half;
    bool hasB = iB < E;
    // issue both edges' loads before either store (independent chains -> 2x MLP)
    int cellA = dst[i] * 8 + et[i];
    int cellB = hasB ? dst[iB] * 8 + et[iB] : 0;
    int rA = rp[cellA];
    int rB = hasB ? rp[cellB] : 0;
    int oA = eoff[i];
    int oB = hasB ? eoff[iB] : 0;
    int sA = src[i];
    int sB = hasB ? src[iB] : 0;
    srcs[rA + oA] = sA;
    if (hasB) srcs[rB + oB] = sB;
}

// ---------------- aggregate v4: wave/dst; per-cell quads; scalar dwordx4 src loads
__global__ __launch_bounds__(256) void aggregate_kernel(const __bf16* __restrict__ xb,
                                                        const int* __restrict__ srcs,
                                                        const int* __restrict__ rp,
                                                        const float* __restrict__ invdeg,
                                                        __bf16* __restrict__ Sx, int N) {
    int d0 = blockIdx.x * 4 + (threadIdx.x >> 6);
    if (d0 >= N) return;
    int d = __builtin_amdgcn_readfirstlane(d0);
    int lane = threadIdx.x & 63;

    int rpv[9];
#pragma unroll
    for (int r = 0; r < 9; ++r) rpv[r] = rp[d * 8 + r];   // scalar loads (uniform)

    float facc[NREL];
#pragma unroll
    for (int r = 0; r < NREL; ++r) {                      // r compile-time -> named acc regs
        float acc = 0.f;
        for (int q = rpv[r]; q < rpv[r + 1]; q += 4) {    // uniform bounds, step 4
            int4 sv = *reinterpret_cast<const int4*>(srcs + q);   // s_load_dwordx4
            float v0 = (float)xb[(size_t)sv.x * DIM + lane];      // 4 independent gathers
            float v1 = (float)xb[(size_t)sv.y * DIM + lane];      // (sentinel N -> zero row)
            float v2 = (float)xb[(size_t)sv.z * DIM + lane];
            float v3 = (float)xb[(size_t)sv.w * DIM + lane];
            acc += (v0 + v1) + (v2 + v3);
        }
        facc[r] = acc;
    }

    float inv = invdeg[d];
    bf16x8 h;
#pragma unroll
    for (int r = 0; r < NREL; ++r) h[r] = (__bf16)(facc[r] * inv);
    // k-permuted row: element k = ch*8 + r, lane stores ch=lane -> 16B contiguous
    *reinterpret_cast<bf16x8*>(Sx + (size_t)d * KS + lane * 8) = h;
}

// ---------------- GEMM v2: W-in-registers (A-operand), Sx streamed (B-operand)
// NOTE: xout MUST NOT alias xin (waves share rows, split channels -> WAR race if in-place).
__global__ __launch_bounds__(256) void gemm_kernel(const __bf16* __restrict__ Sx,
                                                   const __bf16* __restrict__ xin,
                                                   const __bf16* __restrict__ Wt,    // [64][576]
                                                   const float* __restrict__ bias_l, // [64]
                                                   __bf16* __restrict__ xout, int N) {
    int wave = threadIdx.x >> 6;
    int lane = threadIdx.x & 63;
    int l15 = lane & 15;
    int lg  = lane >> 4;

    // hoist A (weights) into registers: 18 x 4 VGPRs = 72 VGPRs
    bf16x8 afrag[KTOT / 32];
    {
        const __bf16* wrow = Wt + (size_t)(16 * wave + l15) * KTOT + lg * 8;
#pragma unroll
        for (int kk = 0; kk < KTOT / 32; ++kk)
            afrag[kk] = *reinterpret_cast<const bf16x8*>(wrow + kk * 32);
    }
    int cbase = 16 * wave + 4 * lg;
    f32x4 bias4 = *reinterpret_cast<const f32x4*>(bias_l + cbase);

    int ntiles = (N + 15) >> 4;
    for (int tile = blockIdx.x; tile < ntiles; tile += gridDim.x) {
        int n = tile * 16 + l15;
        int nc = (n < N) ? n : (N - 1);                   // clamped load, guarded store
        const __bf16* srow = Sx  + (size_t)nc * KS  + lg * 8;
        const __bf16* xrow = xin + (size_t)nc * DIM + lg * 8;

        f32x4 acc = (f32x4){0.f, 0.f, 0.f, 0.f};
#pragma unroll
        for (int kk = 0; kk < KS / 32; ++kk) {
            bf16x8 bv = *reinterpret_cast<const bf16x8*>(srow + kk * 32);
            acc = __builtin_amdgcn_mfma_f32_16x16x32_bf16(afrag[kk], bv, acc, 0, 0, 0);
        }
#pragma unroll
        for (int kk = 0; kk < DIM / 32; ++kk) {
            bf16x8 bv = *reinterpret_cast<const bf16x8*>(xrow + kk * 32);
            acc = __builtin_amdgcn_mfma_f32_16x16x32_bf16(afrag[KS / 32 + kk], bv, acc, 0, 0, 0);
        }

        if (n < N) {
            bf16x4 h;
#pragma unroll
            for (int i = 0; i < 4; ++i)
                h[i] = (__bf16)fmaxf(acc[i] + bias4[i], 0.f);
            *reinterpret_cast<bf16x4*>(xout + (size_t)n * DIM + cbase) = h;
        }
    }
}

// ---------------- score ----------------
__global__ __launch_bounds__(256) void score_kernel(const __bf16* __restrict__ xb,
                                                    const int* __restrict__ s,
                                                    const int* __restrict__ t,
                                                    float* __restrict__ out, int T) {
    int i = blockIdx.x * 4 + (threadIdx.x >> 6);
    if (i >= T) return;
    int lane = threadIdx.x & 63;
    float p = (float)xb[(size_t)s[i] * DIM + lane] * (float)xb[(size_t)t[i] * DIM + lane];
#pragma unroll
    for (int off = 32; off > 0; off >>= 1) p += __shfl_down(p, off, 64);
    if (lane == 0) out[i] = p;
}

extern "C" void kernel_launch(void* const* d_in, const int* in_sizes, int n_in,
                              void* d_out, int out_size, void* d_ws, size_t ws_size,
                              hipStream_t stream) {
    const int*   x_idx  = (const int*)d_in[0];
    const int*   eidx   = (const int*)d_in[1];   // [2,E]
    const int*   etyp   = (const int*)d_in[2];   // [E]
    const int*   tidx   = (const int*)d_in[3];   // [2,T]
    const float* emb    = (const float*)d_in[4]; // [N,64]
    const float* weight = (const float*)d_in[5]; // [L,8,64,64]
    const float* root   = (const float*)d_in[6]; // [L,64,64]
    const float* bias   = (const float*)d_in[7]; // [L,64]

    int N = in_sizes[0];
    int E = in_sizes[2];
    int T = in_sizes[3] / 2;
    int L = in_sizes[5] / (NREL * DIM * DIM);

    const int* src = eidx;
    const int* dst = eidx + E;
    const int* ts  = tidx;
    const int* tt  = tidx + T;
    float* out = (float*)d_out;

    int epad_cap = E + 3 * N * NREL + 64;   // worst-case padded edge count

    // ---- workspace carve-up ----
    char* p = (char*)d_ws;
    auto alloc = [&](size_t bytes) -> void* {
        void* r = (void*)p;
        p += (bytes + 255) & ~(size_t)255;
        return r;
    };
    __bf16* Sx      = (__bf16*)alloc((size_t)N * KS * sizeof(__bf16));
    __bf16* xb0     = (__bf16*)alloc((size_t)(N + 1) * DIM * sizeof(__bf16));  // +1 zero row
    __bf16* xb1     = (__bf16*)alloc((size_t)(N + 1) * DIM * sizeof(__bf16));  // ping-pong
    __bf16* Wt      = (__bf16*)alloc((size_t)L * 64 * KTOT * sizeof(__bf16));
    int*    srcs    = (int*)   alloc((size_t)epad_cap * sizeof(int));
    int*    eoff    = (int*)   alloc((size_t)E * sizeof(int));
    int*    deg8    = (int*)   alloc((size_t)N * 8 * DSTR * sizeof(int));  // 16B-strided cells
    int*    rp      = (int*)   alloc(((size_t)N * 8 + 1) * sizeof(int));
    int*    offs    = (int*)   alloc((size_t)N * sizeof(int));
    float*  invdeg  = (float*) alloc((size_t)N * sizeof(float));
    int*    bsum    = (int*)   alloc(1024 * sizeof(int));

    int nb = (N + 255) / 256;

    hipMemsetAsync(deg8, 0, (size_t)N * 8 * DSTR * sizeof(int), stream);
    histgather_kernel<<<((size_t)N * DIM + 255) / 256, 256, 0, stream>>>(
        dst, etyp, deg8, eoff, x_idx, emb, xb0, xb1, srcs, N, E, epad_cap);
    scan1_kernel<<<nb, 256, 0, stream>>>(deg8, offs, bsum, invdeg, N);
    {
        int wtotal = L * 64 * KTOT;
        int wblocks = 1 + (wtotal + 511) / 512;
        scan2wcat_kernel<<<wblocks, 512, 0, stream>>>(bsum, nb, weight, root, Wt, L);
    }
    rpbuild_kernel<<<nb, 256, 0, stream>>>(deg8, offs, bsum, rp, N);
    {
        int half = (E + 1) / 2;
        bucket_kernel<<<(half + 255) / 256, 256, 0, stream>>>(src, dst, etyp, rp, eoff, srcs, E);
    }

    __bf16* xcur = xb0;
    __bf16* xnxt = xb1;
    for (int l = 0; l < L; ++l) {
        aggregate_kernel<<<(N + 3) / 4, 256, 0, stream>>>(xcur, srcs, rp, invdeg, Sx, N);
        gemm_kernel<<<1024, 256, 0, stream>>>(Sx, xcur,
                                              Wt + (size_t)l * 64 * KTOT,
                                              bias + (size_t)l * DIM,
                                              xnxt, N);
        __bf16* tmp = xcur; xcur = xnxt; xnxt = tmp;
    }

    score_kernel<<<(T + 3) / 4, 256, 0, stream>>>(xcur, ts, tt, out, T);
}

// Round 3
// 432.856 us; speedup vs baseline: 1.0513x; 1.0513x over previous
//
#include <hip/hip_runtime.h>
#include <hip/hip_bf16.h>

#define DIM 64
#define NREL 8
#define KS 512              // Sx width (k-permuted: k = ch*8 + r)
#define KTOT 576            // GEMM K: 512 + 64 root
#define PADK 520            // LDS row stride in bf16: 512 + 8 pad (1040B) -> uniform bank spread

typedef __bf16 bf16x8 __attribute__((ext_vector_type(8)));
typedef __bf16 bf16x4 __attribute__((ext_vector_type(4)));
typedef float  f32x4  __attribute__((ext_vector_type(4)));

// ---------------- fused: hist (rank-returning) + initial gather + sentinels ----------------
__global__ __launch_bounds__(256) void histgather_kernel(const int* __restrict__ dst,
                                                         const int* __restrict__ et,
                                                         int* __restrict__ deg8,
                                                         int* __restrict__ eoff,
                                                         const int* __restrict__ x_idx,
                                                         const float* __restrict__ emb,
                                                         __bf16* __restrict__ xb0,
                                                         __bf16* __restrict__ xb1,
                                                         int* __restrict__ srcs,
                                                         int N, int E, int epad_cap) {
    int i = blockIdx.x * 256 + threadIdx.x;
    if (i < N * DIM) {
        int n = i >> 6;
        int c = i & 63;
        xb0[i] = (__bf16)emb[(size_t)x_idx[n] * DIM + c];
    }
    if (i < DIM) {                                        // sentinel zero rows (index N)
        xb0[(size_t)N * DIM + i] = (__bf16)0.f;
        xb1[(size_t)N * DIM + i] = (__bf16)0.f;
    }
    if (i < epad_cap) srcs[i] = N;                        // padding -> sentinel
    if (i < E) eoff[i] = atomicAdd(&deg8[dst[i] * 8 + et[i]], 1);  // rank within cell
}

// ---------------- scan1 over per-dst PADDED totals + invdeg (true deg) ----------------
__global__ __launch_bounds__(256) void scan1_kernel(const int* __restrict__ deg8,
                                                    int* __restrict__ offs,
                                                    int* __restrict__ bsum,
                                                    float* __restrict__ invdeg, int N) {
    __shared__ int sd[256];
    int tid = threadIdx.x;
    int d = blockIdx.x * 256 + tid;
    int vpad = 0;
    if (d < N) {
        int vtrue = 0;
#pragma unroll
        for (int r = 0; r < NREL; ++r) {
            int dv = deg8[d * 8 + r];
            vtrue += dv;
            vpad += (dv + 3) & ~3;
        }
        invdeg[d] = 1.0f / fmaxf((float)vtrue, 1.0f);
    }
    sd[tid] = vpad;
    __syncthreads();
#pragma unroll
    for (int off = 1; off < 256; off <<= 1) {
        int t = (tid >= off) ? sd[tid - off] : 0;
        __syncthreads();
        sd[tid] += t;
        __syncthreads();
    }
    if (d < N) offs[d] = sd[tid] - vpad;
    if (tid == 255) bsum[blockIdx.x] = sd[255];
}

// ---------------- scan2 (block 0) + wcat (blocks >= 1) fused ----------------
// Wt[l][c][k]: k<512 -> k=ch*8+r maps weight[l][r][ch][c]; k>=512 -> root[l][k-512][c]
__global__ __launch_bounds__(512) void scan2wcat_kernel(int* __restrict__ bsum, int nb,
                                                        const float* __restrict__ weight,
                                                        const float* __restrict__ root,
                                                        __bf16* __restrict__ Wt, int L) {
    if (blockIdx.x == 0) {
        __shared__ int sd[512];
        int tid = threadIdx.x;
        int v = (tid < nb) ? bsum[tid] : 0;
        sd[tid] = v;
        __syncthreads();
#pragma unroll
        for (int off = 1; off < 512; off <<= 1) {
            int t = (tid >= off) ? sd[tid - off] : 0;
            __syncthreads();
            sd[tid] += t;
            __syncthreads();
        }
        if (tid < nb) bsum[tid] = sd[tid] - v;
    } else {
        int idx = (blockIdx.x - 1) * 512 + threadIdx.x;
        int total = L * 64 * KTOT;
        if (idx >= total) return;
        int l = idx / (64 * KTOT);
        int rem = idx - l * 64 * KTOT;
        int c = rem / KTOT;
        int k = rem - c * KTOT;
        float w;
        if (k < KS) {
            int ch = k >> 3, r = k & 7;
            w = weight[(((l * 8 + r) * 64) + ch) * 64 + c];
        } else {
            w = root[(l * 64 + (k - KS)) * 64 + c];
        }
        Wt[idx] = (__bf16)w;
    }
}

// ---------------- rp_pad build (padded per-cell starts) ----------------
__global__ __launch_bounds__(256) void rpbuild_kernel(const int* __restrict__ deg8,
                                                      const int* __restrict__ offs,
                                                      const int* __restrict__ bsum,
                                                      int* __restrict__ rp,
                                                      int N) {
    int d = blockIdx.x * 256 + threadIdx.x;
    if (d >= N) return;
    int base = offs[d] + bsum[blockIdx.x];
    int run = 0;
#pragma unroll
    for (int r = 0; r < NREL; ++r) {
        rp[d * 8 + r] = base + run;
        run += (deg8[d * 8 + r] + 3) & ~3;
    }
    if (d == N - 1) rp[(size_t)N * 8] = base + run;   // E_pad total
}

// ---------------- bucket: atomic-free scatter, 2 coalesced half-streams per thread
__global__ __launch_bounds__(256) void bucket_kernel(const int* __restrict__ src,
                                                     const int* __restrict__ dst,
                                                     const int* __restrict__ et,
                                                     const int* __restrict__ rp,
                                                     const int* __restrict__ eoff,
                                                     int* __restrict__ srcs, int E) {
    int i = blockIdx.x * 256 + threadIdx.x;
    int half = (E + 1) >> 1;
    if (i >= half) return;
    int iB = i + half;
    bool hasB = iB < E;
    // issue both edges' loads before either store (independent chains -> 2x MLP)
    int cellA = dst[i] * 8 + et[i];
    int cellB = hasB ? dst[iB] * 8 + et[iB] : 0;
    int rA = rp[cellA];
    int rB = hasB ? rp[cellB] : 0;
    int oA = eoff[i];
    int oB = hasB ? eoff[iB] : 0;
    int sA = src[i];
    int sB = hasB ? src[iB] : 0;
    srcs[rA + oA] = sA;
    if (hasB) srcs[rB + oB] = sB;
}

// ---------------- fused aggregate+GEMM: no Sx materialization ----------------
// Block = 4 waves. Per tile of 16 dst rows:
//   phase A: wave w aggregates rows 4w..4w+3 (per-rel quad gathers, as aggregate v4),
//            writes k-permuted 512-wide row to LDS (row stride PADK=520 bf16).
//   phase B: existing W-in-registers GEMM, B-operand from LDS (Sx) + global (xin root term).
// xout MUST NOT alias xin (gathers read other nodes' rows while they're being overwritten).
__global__ __launch_bounds__(256) void aggemm_kernel(const __bf16* __restrict__ xin,
                                                     const int* __restrict__ srcs,
                                                     const int* __restrict__ rp,
                                                     const float* __restrict__ invdeg,
                                                     const __bf16* __restrict__ Wt,    // [64][576]
                                                     const float* __restrict__ bias_l, // [64]
                                                     __bf16* __restrict__ xout, int N) {
    __shared__ __align__(16) __bf16 S[16 * PADK];
    int wave = threadIdx.x >> 6;
    int lane = threadIdx.x & 63;
    int l15 = lane & 15;
    int lg  = lane >> 4;

    // hoist A (weights) into registers once per block: 18 x 4 VGPRs = 72 VGPRs
    bf16x8 afrag[KTOT / 32];
    {
        const __bf16* wrow = Wt + (size_t)(16 * wave + l15) * KTOT + lg * 8;
#pragma unroll
        for (int kk = 0; kk < KTOT / 32; ++kk)
            afrag[kk] = *reinterpret_cast<const bf16x8*>(wrow + kk * 32);
    }
    int cbase = 16 * wave + 4 * lg;
    f32x4 bias4 = *reinterpret_cast<const f32x4*>(bias_l + cbase);

    int ntiles = (N + 15) >> 4;
    for (int tile = blockIdx.x; tile < ntiles; tile += gridDim.x) {
        // ---------- phase A: aggregation, 4 rows per wave ----------
#pragma unroll
        for (int rr = 0; rr < 4; ++rr) {
            int d0 = tile * 16 + wave * 4 + rr;
            if (d0 >= N) d0 = N - 1;                          // clamped (tail tile only)
            int d = __builtin_amdgcn_readfirstlane(d0);
            int rpv[9];
#pragma unroll
            for (int r = 0; r < 9; ++r) rpv[r] = rp[d * 8 + r];   // uniform scalar loads
            float facc[NREL];
#pragma unroll
            for (int r = 0; r < NREL; ++r) {
                float acc = 0.f;
                for (int q = rpv[r]; q < rpv[r + 1]; q += 4) {    // uniform bounds, step 4
                    int4 sv = *reinterpret_cast<const int4*>(srcs + q);
                    float v0 = (float)xin[(size_t)sv.x * DIM + lane];  // 4 independent gathers
                    float v1 = (float)xin[(size_t)sv.y * DIM + lane];  // (sentinel N -> zero row)
                    float v2 = (float)xin[(size_t)sv.z * DIM + lane];
                    float v3 = (float)xin[(size_t)sv.w * DIM + lane];
                    acc += (v0 + v1) + (v2 + v3);
                }
                facc[r] = acc;
            }
            float inv = invdeg[d];
            bf16x8 h;
#pragma unroll
            for (int r = 0; r < NREL; ++r) h[r] = (__bf16)(facc[r] * inv);
            // k-permuted row: element k = ch*8 + r, lane holds ch=lane -> 16B contiguous
            *reinterpret_cast<bf16x8*>(&S[(wave * 4 + rr) * PADK + lane * 8]) = h;
        }
        __syncthreads();

        // ---------- phase B: 16x64 GEMM over K=576 ----------
        int n = tile * 16 + l15;
        int nc = (n < N) ? n : (N - 1);                   // clamped load, guarded store
        const __bf16* xrow = xin + (size_t)nc * DIM + lg * 8;
        const __bf16* srow = &S[l15 * PADK + lg * 8];

        f32x4 acc = (f32x4){0.f, 0.f, 0.f, 0.f};
#pragma unroll
        for (int kk = 0; kk < KS / 32; ++kk) {
            bf16x8 bv = *reinterpret_cast<const bf16x8*>(srow + kk * 32);
            acc = __builtin_amdgcn_mfma_f32_16x16x32_bf16(afrag[kk], bv, acc, 0, 0, 0);
        }
#pragma unroll
        for (int kk = 0; kk < DIM / 32; ++kk) {
            bf16x8 bv = *reinterpret_cast<const bf16x8*>(xrow + kk * 32);
            acc = __builtin_amdgcn_mfma_f32_16x16x32_bf16(afrag[KS / 32 + kk], bv, acc, 0, 0, 0);
        }

        if (n < N) {
            bf16x4 h;
#pragma unroll
            for (int i = 0; i < 4; ++i)
                h[i] = (__bf16)fmaxf(acc[i] + bias4[i], 0.f);
            *reinterpret_cast<bf16x4*>(xout + (size_t)n * DIM + cbase) = h;
        }
        __syncthreads();                                  // WAR: next tile rewrites S
    }
}

// ---------------- score ----------------
__global__ __launch_bounds__(256) void score_kernel(const __bf16* __restrict__ xb,
                                                    const int* __restrict__ s,
                                                    const int* __restrict__ t,
                                                    float* __restrict__ out, int T) {
    int i = blockIdx.x * 4 + (threadIdx.x >> 6);
    if (i >= T) return;
    int lane = threadIdx.x & 63;
    float p = (float)xb[(size_t)s[i] * DIM + lane] * (float)xb[(size_t)t[i] * DIM + lane];
#pragma unroll
    for (int off = 32; off > 0; off >>= 1) p += __shfl_down(p, off, 64);
    if (lane == 0) out[i] = p;
}

extern "C" void kernel_launch(void* const* d_in, const int* in_sizes, int n_in,
                              void* d_out, int out_size, void* d_ws, size_t ws_size,
                              hipStream_t stream) {
    const int*   x_idx  = (const int*)d_in[0];
    const int*   eidx   = (const int*)d_in[1];   // [2,E]
    const int*   etyp   = (const int*)d_in[2];   // [E]
    const int*   tidx   = (const int*)d_in[3];   // [2,T]
    const float* emb    = (const float*)d_in[4]; // [N,64]
    const float* weight = (const float*)d_in[5]; // [L,8,64,64]
    const float* root   = (const float*)d_in[6]; // [L,64,64]
    const float* bias   = (const float*)d_in[7]; // [L,64]

    int N = in_sizes[0];
    int E = in_sizes[2];
    int T = in_sizes[3] / 2;
    int L = in_sizes[5] / (NREL * DIM * DIM);

    const int* src = eidx;
    const int* dst = eidx + E;
    const int* ts  = tidx;
    const int* tt  = tidx + T;
    float* out = (float*)d_out;

    int epad_cap = E + 3 * N * NREL + 64;   // worst-case padded edge count

    // ---- workspace carve-up ----
    char* p = (char*)d_ws;
    auto alloc = [&](size_t bytes) -> void* {
        void* r = (void*)p;
        p += (bytes + 255) & ~(size_t)255;
        return r;
    };
    __bf16* xb0     = (__bf16*)alloc((size_t)(N + 1) * DIM * sizeof(__bf16));  // +1 zero row
    __bf16* xb1     = (__bf16*)alloc((size_t)(N + 1) * DIM * sizeof(__bf16));  // ping-pong
    __bf16* Wt      = (__bf16*)alloc((size_t)L * 64 * KTOT * sizeof(__bf16));
    int*    srcs    = (int*)   alloc((size_t)epad_cap * sizeof(int));
    int*    eoff    = (int*)   alloc((size_t)E * sizeof(int));
    int*    deg8    = (int*)   alloc((size_t)N * 8 * sizeof(int));
    int*    rp      = (int*)   alloc(((size_t)N * 8 + 1) * sizeof(int));
    int*    offs    = (int*)   alloc((size_t)N * sizeof(int));
    float*  invdeg  = (float*) alloc((size_t)N * sizeof(float));
    int*    bsum    = (int*)   alloc(1024 * sizeof(int));

    int nb = (N + 255) / 256;

    hipMemsetAsync(deg8, 0, (size_t)N * 8 * sizeof(int), stream);
    histgather_kernel<<<((size_t)N * DIM + 255) / 256, 256, 0, stream>>>(
        dst, etyp, deg8, eoff, x_idx, emb, xb0, xb1, srcs, N, E, epad_cap);
    scan1_kernel<<<nb, 256, 0, stream>>>(deg8, offs, bsum, invdeg, N);
    {
        int wtotal = L * 64 * KTOT;
        int wblocks = 1 + (wtotal + 511) / 512;
        scan2wcat_kernel<<<wblocks, 512, 0, stream>>>(bsum, nb, weight, root, Wt, L);
    }
    rpbuild_kernel<<<nb, 256, 0, stream>>>(deg8, offs, bsum, rp, N);
    {
        int half = (E + 1) / 2;
        bucket_kernel<<<(half + 255) / 256, 256, 0, stream>>>(src, dst, etyp, rp, eoff, srcs, E);
    }

    __bf16* xcur = xb0;
    __bf16* xnxt = xb1;
    for (int l = 0; l < L; ++l) {
        aggemm_kernel<<<2048, 256, 0, stream>>>(xcur, srcs, rp, invdeg,
                                                Wt + (size_t)l * 64 * KTOT,
                                                bias + (size_t)l * DIM,
                                                xnxt, N);
        __bf16* tmp = xcur; xcur = xnxt; xnxt = tmp;
    }

    score_kernel<<<(T + 3) / 4, 256, 0, stream>>>(xcur, ts, tt, out, T);
}

// Round 4
// 406.860 us; speedup vs baseline: 1.1185x; 1.0639x over previous
//
#include <hip/hip_runtime.h>
#include <hip/hip_bf16.h>

#define DIM 64
#define NREL 8
#define KTOT 576            // Wt2 rows: 512 rel-cols + 64 root cols

typedef __bf16 bf16x8 __attribute__((ext_vector_type(8)));
typedef __bf16 bf16x4 __attribute__((ext_vector_type(4)));
typedef float  f32x4  __attribute__((ext_vector_type(4)));

// ---------------- fused: hist (rank-returning) + initial gather + sentinels ----------------
__global__ __launch_bounds__(256) void histgather_kernel(const int* __restrict__ dst,
                                                         const int* __restrict__ et,
                                                         int* __restrict__ deg8,
                                                         int* __restrict__ eoff,
                                                         const int* __restrict__ x_idx,
                                                         const float* __restrict__ emb,
                                                         __bf16* __restrict__ xb0,
                                                         __bf16* __restrict__ hbuf,
                                                         int* __restrict__ srcs,
                                                         int N, int E, int epad_cap) {
    int i = blockIdx.x * 256 + threadIdx.x;
    if (i < N * DIM) {
        int n = i >> 6;
        int c = i & 63;
        xb0[i] = (__bf16)emb[(size_t)x_idx[n] * DIM + c];
    }
    if (i < DIM) {                                        // sentinel zero row in h (gidx = 8N)
        hbuf[(size_t)N * NREL * DIM + i] = (__bf16)0.f;
    }
    if (i < epad_cap) srcs[i] = N * NREL;                 // padding -> sentinel gidx
    if (i < E) eoff[i] = atomicAdd(&deg8[dst[i] * 8 + et[i]], 1);  // rank within (dst,rel) cell
}

// ---------------- scan1 over per-dst ROW-PADDED totals + invdeg (true deg) ----------------
__global__ __launch_bounds__(256) void scan1_kernel(const int* __restrict__ deg8,
                                                    int* __restrict__ offs,
                                                    int* __restrict__ bsum,
                                                    float* __restrict__ invdeg, int N) {
    __shared__ int sd[256];
    int tid = threadIdx.x;
    int d = blockIdx.x * 256 + tid;
    int vpad = 0;
    if (d < N) {
        int vtrue = 0;
#pragma unroll
        for (int r = 0; r < NREL; ++r) vtrue += deg8[d * 8 + r];
        vpad = (vtrue + 3) & ~3;                          // pad per ROW (not per cell)
        invdeg[d] = 1.0f / fmaxf((float)vtrue, 1.0f);
    }
    sd[tid] = vpad;
    __syncthreads();
#pragma unroll
    for (int off = 1; off < 256; off <<= 1) {
        int t = (tid >= off) ? sd[tid - off] : 0;
        __syncthreads();
        sd[tid] += t;
        __syncthreads();
    }
    if (d < N) offs[d] = sd[tid] - vpad;
    if (tid == 255) bsum[blockIdx.x] = sd[255];
}

// ---------------- scan2 (block 0) + wcat (blocks >= 1) fused ----------------
// Wt2[l][row][ch]: row<512 -> row=r*64+c maps weight[l][r][ch][c] (rel-transform A-operand);
//                  row>=512 -> c=row-512 maps root[l][ch][c] (root A-operand)
__global__ __launch_bounds__(512) void scan2wcat_kernel(int* __restrict__ bsum, int nb,
                                                        const float* __restrict__ weight,
                                                        const float* __restrict__ root,
                                                        __bf16* __restrict__ Wt2, int L) {
    if (blockIdx.x == 0) {
        __shared__ int sd[512];
        int tid = threadIdx.x;
        int v = (tid < nb) ? bsum[tid] : 0;
        sd[tid] = v;
        __syncthreads();
#pragma unroll
        for (int off = 1; off < 512; off <<= 1) {
            int t = (tid >= off) ? sd[tid - off] : 0;
            __syncthreads();
            sd[tid] += t;
            __syncthreads();
        }
        if (tid < nb) bsum[tid] = sd[tid] - v;
    } else {
        int idx = (blockIdx.x - 1) * 512 + threadIdx.x;
        int total = L * KTOT * DIM;
        if (idx >= total) return;
        int l = idx / (KTOT * DIM);
        int rem = idx - l * (KTOT * DIM);
        int row = rem / DIM;
        int ch = rem - row * DIM;
        float w;
        if (row < 512) {
            int r = row >> 6, c = row & 63;
            w = weight[(((l * 8 + r) * 64) + ch) * 64 + c];
        } else {
            w = root[(l * 64 + ch) * 64 + (row - 512)];
        }
        Wt2[idx] = (__bf16)w;
    }
}

// ---------------- rp build: exact cell starts within row-padded slot space ----------------
__global__ __launch_bounds__(256) void rpbuild_kernel(const int* __restrict__ deg8,
                                                      const int* __restrict__ offs,
                                                      const int* __restrict__ bsum,
                                                      int* __restrict__ rp,
                                                      int N) {
    int d = blockIdx.x * 256 + threadIdx.x;
    if (d >= N) return;
    int base = offs[d] + bsum[blockIdx.x];
    int run = 0;
#pragma unroll
    for (int r = 0; r < NREL; ++r) {
        rp[d * 8 + r] = base + run;
        run += deg8[d * 8 + r];                           // exact (no per-cell pad)
    }
    if (d == N - 1) rp[(size_t)N * 8] = base + ((run + 3) & ~3);   // padded total
}

// ---------------- bucket: atomic-free scatter of PACKED gather index src*8+rel ----------------
__global__ __launch_bounds__(256) void bucket_kernel(const int* __restrict__ src,
                                                     const int* __restrict__ dst,
                                                     const int* __restrict__ et,
                                                     const int* __restrict__ rp,
                                                     const int* __restrict__ eoff,
                                                     int* __restrict__ srcs, int E) {
    int i = blockIdx.x * 256 + threadIdx.x;
    int half = (E + 1) >> 1;
    if (i >= half) return;
    int iB = i + half;
    bool hasB = iB < E;
    int etA = et[i];
    int etB = hasB ? et[iB] : 0;
    int cellA = dst[i] * 8 + etA;
    int cellB = hasB ? dst[iB] * 8 + etB : 0;
    int rA = rp[cellA];
    int rB = hasB ? rp[cellB] : 0;
    int oA = eoff[i];
    int oB = hasB ? eoff[iB] : 0;
    int sA = src[i];
    int sB = hasB ? src[iB] : 0;
    srcs[rA + oA] = sA * NREL + etA;                      // packed gidx
    if (hasB) srcs[rB + oB] = sB * NREL + etB;
}

// ---------------- transform: h[n][r*64+c] = sum_ch x[n][ch] * W[l][r][ch][c] ----------------
// one 16-node tile per block; 8 col-passes of 64; A (Wt2) hoisted to registers.
__global__ __launch_bounds__(256) void transform_kernel(const __bf16* __restrict__ xin,
                                                        const __bf16* __restrict__ Wt2,  // [576][64]
                                                        __bf16* __restrict__ h, int N) {
    int wave = threadIdx.x >> 6;
    int lane = threadIdx.x & 63;
    int l15 = lane & 15;
    int lg  = lane >> 4;

    bf16x8 afrag[8][2];
#pragma unroll
    for (int p = 0; p < 8; ++p) {
        const __bf16* wrow = Wt2 + (size_t)(p * 64 + 16 * wave + l15) * DIM + lg * 8;
        afrag[p][0] = *reinterpret_cast<const bf16x8*>(wrow);
        afrag[p][1] = *reinterpret_cast<const bf16x8*>(wrow + 32);
    }

    int n = blockIdx.x * 16 + l15;
    int nc = (n < N) ? n : (N - 1);
    const __bf16* xrow = xin + (size_t)nc * DIM + lg * 8;
    bf16x8 bv0 = *reinterpret_cast<const bf16x8*>(xrow);
    bf16x8 bv1 = *reinterpret_cast<const bf16x8*>(xrow + 32);

#pragma unroll
    for (int p = 0; p < 8; ++p) {
        f32x4 acc = (f32x4){0.f, 0.f, 0.f, 0.f};
        acc = __builtin_amdgcn_mfma_f32_16x16x32_bf16(afrag[p][0], bv0, acc, 0, 0, 0);
        acc = __builtin_amdgcn_mfma_f32_16x16x32_bf16(afrag[p][1], bv1, acc, 0, 0, 0);
        if (n < N) {
            bf16x4 hv;
#pragma unroll
            for (int i = 0; i < 4; ++i) hv[i] = (__bf16)acc[i];
            *reinterpret_cast<bf16x4*>(h + (size_t)n * (NREL * DIM) + p * 64 + 16 * wave + 4 * lg) = hv;
        }
    }
}

// ---------------- aggroot: gather-sum of h rows (single loop/row) + root GEMM epilogue ----
__global__ __launch_bounds__(256) void aggroot_kernel(const __bf16* __restrict__ h,
                                                      const __bf16* __restrict__ xin,
                                                      const int* __restrict__ srcs,
                                                      const int* __restrict__ rp,
                                                      const float* __restrict__ invdeg,
                                                      const __bf16* __restrict__ Wt2,   // rows 512..575
                                                      const float* __restrict__ bias_l, // [64]
                                                      __bf16* __restrict__ xout, int N) {
    __shared__ __align__(16) float S16[16][68];           // 68: pad -> conflict-free epilogue reads
    int wave = threadIdx.x >> 6;
    int lane = threadIdx.x & 63;
    int l15 = lane & 15;
    int lg  = lane >> 4;

    bf16x8 ar0, ar1;
    {
        const __bf16* wrow = Wt2 + (size_t)(512 + 16 * wave + l15) * DIM + lg * 8;
        ar0 = *reinterpret_cast<const bf16x8*>(wrow);
        ar1 = *reinterpret_cast<const bf16x8*>(wrow + 32);
    }
    int cbase = 16 * wave + 4 * lg;
    f32x4 bias4 = *reinterpret_cast<const f32x4*>(bias_l + cbase);

    int tile = blockIdx.x;

    // ---------- phase A: 4 rows per wave, one loop per row, 8 gathers in flight ----------
#pragma unroll
    for (int rr = 0; rr < 4; ++rr) {
        int d0 = tile * 16 + wave * 4 + rr;
        if (d0 >= N) d0 = N - 1;                          // tail tile only
        int d = __builtin_amdgcn_readfirstlane(d0);
        int qb = rp[d * 8];
        int qe = rp[d * 8 + 8];                           // next row's base (= padded end)
        float acc = 0.f;
        int q = qb;
        for (; q + 8 <= qe; q += 8) {                     // 2 quads/iter: 8 independent gathers
            int4 sa = *reinterpret_cast<const int4*>(srcs + q);
            int4 sb = *reinterpret_cast<const int4*>(srcs + q + 4);
            float v0 = (float)h[(size_t)sa.x * DIM + lane];
            float v1 = (float)h[(size_t)sa.y * DIM + lane];
            float v2 = (float)h[(size_t)sa.z * DIM + lane];
            float v3 = (float)h[(size_t)sa.w * DIM + lane];
            float v4 = (float)h[(size_t)sb.x * DIM + lane];
            float v5 = (float)h[(size_t)sb.y * DIM + lane];
            float v6 = (float)h[(size_t)sb.z * DIM + lane];
            float v7 = (float)h[(size_t)sb.w * DIM + lane];
            acc += ((v0 + v1) + (v2 + v3)) + ((v4 + v5) + (v6 + v7));
        }
        if (q < qe) {                                     // one remaining quad
            int4 sa = *reinterpret_cast<const int4*>(srcs + q);
            float v0 = (float)h[(size_t)sa.x * DIM + lane];
            float v1 = (float)h[(size_t)sa.y * DIM + lane];
            float v2 = (float)h[(size_t)sa.z * DIM + lane];
            float v3 = (float)h[(size_t)sa.w * DIM + lane];
            acc += (v0 + v1) + (v2 + v3);
        }
        S16[wave * 4 + rr][lane] = acc * invdeg[d];
    }
    __syncthreads();

    // ---------- phase B: root GEMM (K=64) + aggregate epilogue ----------
    int n = tile * 16 + l15;
    int nc = (n < N) ? n : (N - 1);
    const __bf16* xrow = xin + (size_t)nc * DIM + lg * 8;
    bf16x8 bv0 = *reinterpret_cast<const bf16x8*>(xrow);
    bf16x8 bv1 = *reinterpret_cast<const bf16x8*>(xrow + 32);
    f32x4 acc = (f32x4){0.f, 0.f, 0.f, 0.f};
    acc = __builtin_amdgcn_mfma_f32_16x16x32_bf16(ar0, bv0, acc, 0, 0, 0);
    acc = __builtin_amdgcn_mfma_f32_16x16x32_bf16(ar1, bv1, acc, 0, 0, 0);

    if (n < N) {
        f32x4 ag = *reinterpret_cast<const f32x4*>(&S16[l15][cbase]);
        bf16x4 hv;
#pragma unroll
        for (int i = 0; i < 4; ++i)
            hv[i] = (__bf16)fmaxf(acc[i] + ag[i] + bias4[i], 0.f);
        *reinterpret_cast<bf16x4*>(xout + (size_t)n * DIM + cbase) = hv;
    }
}

// ---------------- score ----------------
__global__ __launch_bounds__(256) void score_kernel(const __bf16* __restrict__ xb,
                                                    const int* __restrict__ s,
                                                    const int* __restrict__ t,
                                                    float* __restrict__ out, int T) {
    int i = blockIdx.x * 4 + (threadIdx.x >> 6);
    if (i >= T) return;
    int lane = threadIdx.x & 63;
    float p = (float)xb[(size_t)s[i] * DIM + lane] * (float)xb[(size_t)t[i] * DIM + lane];
#pragma unroll
    for (int off = 32; off > 0; off >>= 1) p += __shfl_down(p, off, 64);
    if (lane == 0) out[i] = p;
}

extern "C" void kernel_launch(void* const* d_in, const int* in_sizes, int n_in,
                              void* d_out, int out_size, void* d_ws, size_t ws_size,
                              hipStream_t stream) {
    const int*   x_idx  = (const int*)d_in[0];
    const int*   eidx   = (const int*)d_in[1];   // [2,E]
    const int*   etyp   = (const int*)d_in[2];   // [E]
    const int*   tidx   = (const int*)d_in[3];   // [2,T]
    const float* emb    = (const float*)d_in[4]; // [N,64]
    const float* weight = (const float*)d_in[5]; // [L,8,64,64]
    const float* root   = (const float*)d_in[6]; // [L,64,64]
    const float* bias   = (const float*)d_in[7]; // [L,64]

    int N = in_sizes[0];
    int E = in_sizes[2];
    int T = in_sizes[3] / 2;
    int L = in_sizes[5] / (NREL * DIM * DIM);

    const int* src = eidx;
    const int* dst = eidx + E;
    const int* ts  = tidx;
    const int* tt  = tidx + T;
    float* out = (float*)d_out;

    int epad_cap = E + 3 * N + 64;              // per-row pad <= 3

    // ---- workspace carve-up ----
    char* p = (char*)d_ws;
    auto alloc = [&](size_t bytes) -> void* {
        void* r = (void*)p;
        p += (bytes + 255) & ~(size_t)255;
        return r;
    };
    __bf16* hbuf    = (__bf16*)alloc(((size_t)N * NREL + 1) * DIM * sizeof(__bf16)); // +1 zero row
    __bf16* xb0     = (__bf16*)alloc((size_t)N * DIM * sizeof(__bf16));
    __bf16* xb1     = (__bf16*)alloc((size_t)N * DIM * sizeof(__bf16));
    __bf16* Wt2     = (__bf16*)alloc((size_t)L * KTOT * DIM * sizeof(__bf16));
    int*    srcs    = (int*)   alloc((size_t)epad_cap * sizeof(int));
    int*    eoff    = (int*)   alloc((size_t)E * sizeof(int));
    int*    deg8    = (int*)   alloc((size_t)N * 8 * sizeof(int));
    int*    rp      = (int*)   alloc(((size_t)N * 8 + 1) * sizeof(int));
    int*    offs    = (int*)   alloc((size_t)N * sizeof(int));
    float*  invdeg  = (float*) alloc((size_t)N * sizeof(float));
    int*    bsum    = (int*)   alloc(1024 * sizeof(int));

    int nb = (N + 255) / 256;
    int ntiles = (N + 15) / 16;

    hipMemsetAsync(deg8, 0, (size_t)N * 8 * sizeof(int), stream);
    histgather_kernel<<<((size_t)N * DIM + 255) / 256, 256, 0, stream>>>(
        dst, etyp, deg8, eoff, x_idx, emb, xb0, hbuf, srcs, N, E, epad_cap);
    scan1_kernel<<<nb, 256, 0, stream>>>(deg8, offs, bsum, invdeg, N);
    {
        int wtotal = L * KTOT * DIM;
        int wblocks = 1 + (wtotal + 511) / 512;
        scan2wcat_kernel<<<wblocks, 512, 0, stream>>>(bsum, nb, weight, root, Wt2, L);
    }
    rpbuild_kernel<<<nb, 256, 0, stream>>>(deg8, offs, bsum, rp, N);
    {
        int half = (E + 1) / 2;
        bucket_kernel<<<(half + 255) / 256, 256, 0, stream>>>(src, dst, etyp, rp, eoff, srcs, E);
    }

    __bf16* xcur = xb0;
    __bf16* xnxt = xb1;
    for (int l = 0; l < L; ++l) {
        transform_kernel<<<ntiles, 256, 0, stream>>>(xcur, Wt2 + (size_t)l * KTOT * DIM, hbuf, N);
        aggroot_kernel<<<ntiles, 256, 0, stream>>>(hbuf, xcur, srcs, rp, invdeg,
                                                   Wt2 + (size_t)l * KTOT * DIM,
                                                   bias + (size_t)l * DIM,
                                                   xnxt, N);
        __bf16* tmp = xcur; xcur = xnxt; xnxt = tmp;
    }

    score_kernel<<<(T + 3) / 4, 256, 0, stream>>>(xcur, ts, tt, out, T);
}

// Round 5
// 367.283 us; speedup vs baseline: 1.2390x; 1.1078x over previous
//
#include <hip/hip_runtime.h>
#include <hip/hip_bf16.h>

#define DIM 64
#define NREL 8
#define KTOT 576            // Wt2 rows: 512 rel-cols + 64 root cols

typedef __bf16 bf16x8 __attribute__((ext_vector_type(8)));
typedef __bf16 bf16x4 __attribute__((ext_vector_type(4)));
typedef float  f32x4  __attribute__((ext_vector_type(4)));

// ---------------- fused: hist (rank-returning) + initial gather + sentinels ----------------
__global__ __launch_bounds__(256) void histgather_kernel(const int* __restrict__ dst,
                                                         const int* __restrict__ et,
                                                         int* __restrict__ deg8,
                                                         int* __restrict__ eoff,
                                                         const int* __restrict__ x_idx,
                                                         const float* __restrict__ emb,
                                                         __bf16* __restrict__ xb0,
                                                         __bf16* __restrict__ hbuf,
                                                         int* __restrict__ srcs,
                                                         int N, int E, int epad_cap) {
    int i = blockIdx.x * 256 + threadIdx.x;
    if (i < N * DIM) {
        int n = i >> 6;
        int c = i & 63;
        xb0[i] = (__bf16)emb[(size_t)x_idx[n] * DIM + c];
    }
    if (i < DIM) {                                        // sentinel zero row in h (gidx = 8N)
        hbuf[(size_t)N * NREL * DIM + i] = (__bf16)0.f;
    }
    if (i < epad_cap) srcs[i] = N * NREL;                 // padding -> sentinel gidx
    if (i < E) eoff[i] = atomicAdd(&deg8[dst[i] * 8 + et[i]], 1);  // rank within (dst,rel) cell
}

// ---------------- scan1 over per-dst ROW-PADDED totals + invdeg (true deg) ----------------
__global__ __launch_bounds__(256) void scan1_kernel(const int* __restrict__ deg8,
                                                    int* __restrict__ offs,
                                                    int* __restrict__ bsum,
                                                    float* __restrict__ invdeg, int N) {
    __shared__ int sd[256];
    int tid = threadIdx.x;
    int d = blockIdx.x * 256 + tid;
    int vpad = 0;
    if (d < N) {
        int vtrue = 0;
#pragma unroll
        for (int r = 0; r < NREL; ++r) vtrue += deg8[d * 8 + r];
        vpad = (vtrue + 3) & ~3;                          // pad per ROW (not per cell)
        invdeg[d] = 1.0f / fmaxf((float)vtrue, 1.0f);
    }
    sd[tid] = vpad;
    __syncthreads();
#pragma unroll
    for (int off = 1; off < 256; off <<= 1) {
        int t = (tid >= off) ? sd[tid - off] : 0;
        __syncthreads();
        sd[tid] += t;
        __syncthreads();
    }
    if (d < N) offs[d] = sd[tid] - vpad;
    if (tid == 255) bsum[blockIdx.x] = sd[255];
}

// ---------------- scan2 (block 0) + wcat (blocks >= 1) fused ----------------
// Wt2[l][row][ch]: row<512 -> row=r*64+c maps weight[l][r][ch][c] (rel-transform A-operand);
//                  row>=512 -> c=row-512 maps root[l][ch][c] (root A-operand)
__global__ __launch_bounds__(512) void scan2wcat_kernel(int* __restrict__ bsum, int nb,
                                                        const float* __restrict__ weight,
                                                        const float* __restrict__ root,
                                                        __bf16* __restrict__ Wt2, int L) {
    if (blockIdx.x == 0) {
        __shared__ int sd[512];
        int tid = threadIdx.x;
        int v = (tid < nb) ? bsum[tid] : 0;
        sd[tid] = v;
        __syncthreads();
#pragma unroll
        for (int off = 1; off < 512; off <<= 1) {
            int t = (tid >= off) ? sd[tid - off] : 0;
            __syncthreads();
            sd[tid] += t;
            __syncthreads();
        }
        if (tid < nb) bsum[tid] = sd[tid] - v;
    } else {
        int idx = (blockIdx.x - 1) * 512 + threadIdx.x;
        int total = L * KTOT * DIM;
        if (idx >= total) return;
        int l = idx / (KTOT * DIM);
        int rem = idx - l * (KTOT * DIM);
        int row = rem / DIM;
        int ch = rem - row * DIM;
        float w;
        if (row < 512) {
            int r = row >> 6, c = row & 63;
            w = weight[(((l * 8 + r) * 64) + ch) * 64 + c];
        } else {
            w = root[(l * 64 + ch) * 64 + (row - 512)];
        }
        Wt2[idx] = (__bf16)w;
    }
}

// ---------------- rp build: exact cell starts within row-padded slot space ----------------
__global__ __launch_bounds__(256) void rpbuild_kernel(const int* __restrict__ deg8,
                                                      const int* __restrict__ offs,
                                                      const int* __restrict__ bsum,
                                                      int* __restrict__ rp,
                                                      int N) {
    int d = blockIdx.x * 256 + threadIdx.x;
    if (d >= N) return;
    int base = offs[d] + bsum[blockIdx.x];
    int run = 0;
#pragma unroll
    for (int r = 0; r < NREL; ++r) {
        rp[d * 8 + r] = base + run;
        run += deg8[d * 8 + r];                           // exact (no per-cell pad)
    }
    if (d == N - 1) rp[(size_t)N * 8] = base + ((run + 3) & ~3);   // padded total
}

// ---------------- bucket: atomic-free scatter of PACKED gather index src*8+rel ----------------
__global__ __launch_bounds__(256) void bucket_kernel(const int* __restrict__ src,
                                                     const int* __restrict__ dst,
                                                     const int* __restrict__ et,
                                                     const int* __restrict__ rp,
                                                     const int* __restrict__ eoff,
                                                     int* __restrict__ srcs, int E) {
    int i = blockIdx.x * 256 + threadIdx.x;
    int half = (E + 1) >> 1;
    if (i >= half) return;
    int iB = i + half;
    bool hasB = iB < E;
    int etA = et[i];
    int etB = hasB ? et[iB] : 0;
    int cellA = dst[i] * 8 + etA;
    int cellB = hasB ? dst[iB] * 8 + etB : 0;
    int rA = rp[cellA];
    int rB = hasB ? rp[cellB] : 0;
    int oA = eoff[i];
    int oB = hasB ? eoff[iB] : 0;
    int sA = src[i];
    int sB = hasB ? src[iB] : 0;
    srcs[rA + oA] = sA * NREL + etA;                      // packed gidx
    if (hasB) srcs[rB + oB] = sB * NREL + etB;
}

// ---------------- transform: h[n][r*64+c] = sum_ch x[n][ch] * W[l][r][ch][c] ----------------
// grid-stride over 16-node tiles; A (Wt2) hoisted to registers ONCE per block.
__global__ __launch_bounds__(256) void transform_kernel(const __bf16* __restrict__ xin,
                                                        const __bf16* __restrict__ Wt2,  // [576][64]
                                                        __bf16* __restrict__ h, int N) {
    int wave = threadIdx.x >> 6;
    int lane = threadIdx.x & 63;
    int l15 = lane & 15;
    int lg  = lane >> 4;

    bf16x8 afrag[8][2];
#pragma unroll
    for (int p = 0; p < 8; ++p) {
        const __bf16* wrow = Wt2 + (size_t)(p * 64 + 16 * wave + l15) * DIM + lg * 8;
        afrag[p][0] = *reinterpret_cast<const bf16x8*>(wrow);
        afrag[p][1] = *reinterpret_cast<const bf16x8*>(wrow + 32);
    }
    int cb = 16 * wave + 4 * lg;

    int ntiles = (N + 15) >> 4;
    for (int tile = blockIdx.x; tile < ntiles; tile += gridDim.x) {
        int n = tile * 16 + l15;
        int nc = (n < N) ? n : (N - 1);
        const __bf16* xrow = xin + (size_t)nc * DIM + lg * 8;
        bf16x8 bv0 = *reinterpret_cast<const bf16x8*>(xrow);
        bf16x8 bv1 = *reinterpret_cast<const bf16x8*>(xrow + 32);

#pragma unroll
        for (int p = 0; p < 8; ++p) {
            f32x4 acc = (f32x4){0.f, 0.f, 0.f, 0.f};
            acc = __builtin_amdgcn_mfma_f32_16x16x32_bf16(afrag[p][0], bv0, acc, 0, 0, 0);
            acc = __builtin_amdgcn_mfma_f32_16x16x32_bf16(afrag[p][1], bv1, acc, 0, 0, 0);
            if (n < N) {
                bf16x4 hv;
#pragma unroll
                for (int i = 0; i < 4; ++i) hv[i] = (__bf16)acc[i];
                *reinterpret_cast<bf16x4*>(h + (size_t)n * (NREL * DIM) + p * 64 + cb) = hv;
            }
        }
    }
}

// ---------------- aggroot: gather-sum of h rows (single loop/row) + root GEMM epilogue ----
__global__ __launch_bounds__(256) void aggroot_kernel(const __bf16* __restrict__ h,
                                                      const __bf16* __restrict__ xin,
                                                      const int* __restrict__ srcs,
                                                      const int* __restrict__ rp,
                                                      const float* __restrict__ invdeg,
                                                      const __bf16* __restrict__ Wt2,   // rows 512..575
                                                      const float* __restrict__ bias_l, // [64]
                                                      __bf16* __restrict__ xout, int N) {
    __shared__ __align__(16) float S16[16][68];           // 68: pad -> conflict-free epilogue reads
    int wave = threadIdx.x >> 6;
    int lane = threadIdx.x & 63;
    int l15 = lane & 15;
    int lg  = lane >> 4;

    bf16x8 ar0, ar1;
    {
        const __bf16* wrow = Wt2 + (size_t)(512 + 16 * wave + l15) * DIM + lg * 8;
        ar0 = *reinterpret_cast<const bf16x8*>(wrow);
        ar1 = *reinterpret_cast<const bf16x8*>(wrow + 32);
    }
    int cbase = 16 * wave + 4 * lg;
    f32x4 bias4 = *reinterpret_cast<const f32x4*>(bias_l + cbase);

    int tile = blockIdx.x;

    // ---------- phase A: 4 rows per wave, one loop per row, 8 gathers in flight ----------
#pragma unroll
    for (int rr = 0; rr < 4; ++rr) {
        int d0 = tile * 16 + wave * 4 + rr;
        if (d0 >= N) d0 = N - 1;                          // tail tile only
        int d = __builtin_amdgcn_readfirstlane(d0);
        int qb = rp[d * 8];
        int qe = rp[d * 8 + 8];                           // next row's base (= padded end)
        float acc = 0.f;
        int q = qb;
        for (; q + 8 <= qe; q += 8) {                     // 2 quads/iter: 8 independent gathers
            int4 sa = *reinterpret_cast<const int4*>(srcs + q);
            int4 sb = *reinterpret_cast<const int4*>(srcs + q + 4);
            float v0 = (float)h[(size_t)sa.x * DIM + lane];
            float v1 = (float)h[(size_t)sa.y * DIM + lane];
            float v2 = (float)h[(size_t)sa.z * DIM + lane];
            float v3 = (float)h[(size_t)sa.w * DIM + lane];
            float v4 = (float)h[(size_t)sb.x * DIM + lane];
            float v5 = (float)h[(size_t)sb.y * DIM + lane];
            float v6 = (float)h[(size_t)sb.z * DIM + lane];
            float v7 = (float)h[(size_t)sb.w * DIM + lane];
            acc += ((v0 + v1) + (v2 + v3)) + ((v4 + v5) + (v6 + v7));
        }
        if (q < qe) {                                     // one remaining quad
            int4 sa = *reinterpret_cast<const int4*>(srcs + q);
            float v0 = (float)h[(size_t)sa.x * DIM + lane];
            float v1 = (float)h[(size_t)sa.y * DIM + lane];
            float v2 = (float)h[(size_t)sa.z * DIM + lane];
            float v3 = (float)h[(size_t)sa.w * DIM + lane];
            acc += (v0 + v1) + (v2 + v3);
        }
        S16[wave * 4 + rr][lane] = acc * invdeg[d];
    }
    __syncthreads();

    // ---------- phase B: root GEMM (K=64) + aggregate epilogue ----------
    int n = tile * 16 + l15;
    int nc = (n < N) ? n : (N - 1);
    const __bf16* xrow = xin + (size_t)nc * DIM + lg * 8;
    bf16x8 bv0 = *reinterpret_cast<const bf16x8*>(xrow);
    bf16x8 bv1 = *reinterpret_cast<const bf16x8*>(xrow + 32);
    f32x4 acc = (f32x4){0.f, 0.f, 0.f, 0.f};
    acc = __builtin_amdgcn_mfma_f32_16x16x32_bf16(ar0, bv0, acc, 0, 0, 0);
    acc = __builtin_amdgcn_mfma_f32_16x16x32_bf16(ar1, bv1, acc, 0, 0, 0);

    if (n < N) {
        f32x4 ag = *reinterpret_cast<const f32x4*>(&S16[l15][cbase]);
        bf16x4 hv;
#pragma unroll
        for (int i = 0; i < 4; ++i)
            hv[i] = (__bf16)fmaxf(acc[i] + ag[i] + bias4[i], 0.f);
        *reinterpret_cast<bf16x4*>(xout + (size_t)n * DIM + cbase) = hv;
    }
}

// ---------------- score ----------------
__global__ __launch_bounds__(256) void score_kernel(const __bf16* __restrict__ xb,
                                                    const int* __restrict__ s,
                                                    const int* __restrict__ t,
                                                    float* __restrict__ out, int T) {
    int i = blockIdx.x * 4 + (threadIdx.x >> 6);
    if (i >= T) return;
    int lane = threadIdx.x & 63;
    float p = (float)xb[(size_t)s[i] * DIM + lane] * (float)xb[(size_t)t[i] * DIM + lane];
#pragma unroll
    for (int off = 32; off > 0; off >>= 1) p += __shfl_down(p, off, 64);
    if (lane == 0) out[i] = p;
}

extern "C" void kernel_launch(void* const* d_in, const int* in_sizes, int n_in,
                              void* d_out, int out_size, void* d_ws, size_t ws_size,
                              hipStream_t stream) {
    const int*   x_idx  = (const int*)d_in[0];
    const int*   eidx   = (const int*)d_in[1];   // [2,E]
    const int*   etyp   = (const int*)d_in[2];   // [E]
    const int*   tidx   = (const int*)d_in[3];   // [2,T]
    const float* emb    = (const float*)d_in[4]; // [N,64]
    const float* weight = (const float*)d_in[5]; // [L,8,64,64]
    const float* root   = (const float*)d_in[6]; // [L,64,64]
    const float* bias   = (const float*)d_in[7]; // [L,64]

    int N = in_sizes[0];
    int E = in_sizes[2];
    int T = in_sizes[3] / 2;
    int L = in_sizes[5] / (NREL * DIM * DIM);

    const int* src = eidx;
    const int* dst = eidx + E;
    const int* ts  = tidx;
    const int* tt  = tidx + T;
    float* out = (float*)d_out;

    int epad_cap = E + 3 * N + 64;              // per-row pad <= 3

    // ---- workspace carve-up ----
    char* p = (char*)d_ws;
    auto alloc = [&](size_t bytes) -> void* {
        void* r = (void*)p;
        p += (bytes + 255) & ~(size_t)255;
        return r;
    };
    __bf16* hbuf    = (__bf16*)alloc(((size_t)N * NREL + 1) * DIM * sizeof(__bf16)); // +1 zero row
    __bf16* xb0     = (__bf16*)alloc((size_t)N * DIM * sizeof(__bf16));
    __bf16* xb1     = (__bf16*)alloc((size_t)N * DIM * sizeof(__bf16));
    __bf16* Wt2     = (__bf16*)alloc((size_t)L * KTOT * DIM * sizeof(__bf16));
    int*    srcs    = (int*)   alloc((size_t)epad_cap * sizeof(int));
    int*    eoff    = (int*)   alloc((size_t)E * sizeof(int));
    int*    deg8    = (int*)   alloc((size_t)N * 8 * sizeof(int));
    int*    rp      = (int*)   alloc(((size_t)N * 8 + 1) * sizeof(int));
    int*    offs    = (int*)   alloc((size_t)N * sizeof(int));
    float*  invdeg  = (float*) alloc((size_t)N * sizeof(float));
    int*    bsum    = (int*)   alloc(1024 * sizeof(int));

    int nb = (N + 255) / 256;
    int ntiles = (N + 15) / 16;

    hipMemsetAsync(deg8, 0, (size_t)N * 8 * sizeof(int), stream);
    histgather_kernel<<<((size_t)N * DIM + 255) / 256, 256, 0, stream>>>(
        dst, etyp, deg8, eoff, x_idx, emb, xb0, hbuf, srcs, N, E, epad_cap);
    scan1_kernel<<<nb, 256, 0, stream>>>(deg8, offs, bsum, invdeg, N);
    {
        int wtotal = L * KTOT * DIM;
        int wblocks = 1 + (wtotal + 511) / 512;
        scan2wcat_kernel<<<wblocks, 512, 0, stream>>>(bsum, nb, weight, root, Wt2, L);
    }
    rpbuild_kernel<<<nb, 256, 0, stream>>>(deg8, offs, bsum, rp, N);
    {
        int half = (E + 1) / 2;
        bucket_kernel<<<(half + 255) / 256, 256, 0, stream>>>(src, dst, etyp, rp, eoff, srcs, E);
    }

    __bf16* xcur = xb0;
    __bf16* xnxt = xb1;
    for (int l = 0; l < L; ++l) {
        transform_kernel<<<2048, 256, 0, stream>>>(xcur, Wt2 + (size_t)l * KTOT * DIM, hbuf, N);
        aggroot_kernel<<<ntiles, 256, 0, stream>>>(hbuf, xcur, srcs, rp, invdeg,
                                                   Wt2 + (size_t)l * KTOT * DIM,
                                                   bias + (size_t)l * DIM,
                                                   xnxt, N);
        __bf16* tmp = xcur; xcur = xnxt; xnxt = tmp;
    }

    score_kernel<<<(T + 3) / 4, 256, 0, stream>>>(xcur, ts, tt, out, T);
}